// Round 1
// baseline (384.438 us; speedup 1.0000x reference)
//
#include <hip/hip_runtime.h>
#include <hip/hip_bf16.h>

#define N 8192
#define D 128
#define BM 128
#define BN 128
#define LDS_STRIDE 136  // D + 8 bf16 pad -> 272 B row stride, breaks bank conflicts

typedef __bf16 bf16x8 __attribute__((ext_vector_type(8)));
typedef __bf16 bf16x4 __attribute__((ext_vector_type(4)));
typedef float f32x4 __attribute__((ext_vector_type(4)));

// Prep: sq[i] = sum_k W[i][k]^2 ; copy weights to out+1 ; zero out[0]
__global__ __launch_bounds__(128) void prep_kernel(const float* __restrict__ W,
                                                   float* __restrict__ out,
                                                   float* __restrict__ sq) {
    const int row = blockIdx.x;
    const int t = threadIdx.x;
    float v = W[row * D + t];
    out[1 + row * D + t] = v;
    float s = v * v;
    for (int off = 32; off > 0; off >>= 1) s += __shfl_down(s, off, 64);
    __shared__ float red[2];
    if ((t & 63) == 0) red[t >> 6] = s;
    __syncthreads();
    if (t == 0) {
        sq[row] = red[0] + red[1];
        if (row == 0) out[0] = 0.0f;
    }
}

__global__ __launch_bounds__(256) void lap_kernel(const float* __restrict__ A,
                                                  const float* __restrict__ W,
                                                  const float* __restrict__ sq,
                                                  float* __restrict__ out) {
    __shared__ __align__(16) __bf16 lds[2 * BM * LDS_STRIDE];
    __bf16* Wi = lds;
    __bf16* Wj = lds + BM * LDS_STRIDE;

    const int tid = threadIdx.x;
    const int j0 = blockIdx.x * BN;
    const int i0 = blockIdx.y * BM;

    // ---- stage W row-tiles (fp32 global -> bf16 LDS), coalesced 512B/row ----
    {
        const int r8 = tid >> 5;          // 0..7
        const int c4 = (tid & 31) * 4;    // float col 0,4,...,124
        for (int pass = 0; pass < 16; ++pass) {
            const int row = pass * 8 + r8;
            const float4 vi = *(const float4*)(&W[(size_t)(i0 + row) * D + c4]);
            const float4 vj = *(const float4*)(&W[(size_t)(j0 + row) * D + c4]);
            bf16x4 bi, bj;
            bi[0] = (__bf16)vi.x; bi[1] = (__bf16)vi.y; bi[2] = (__bf16)vi.z; bi[3] = (__bf16)vi.w;
            bj[0] = (__bf16)vj.x; bj[1] = (__bf16)vj.y; bj[2] = (__bf16)vj.z; bj[3] = (__bf16)vj.w;
            *(bf16x4*)(&Wi[row * LDS_STRIDE + c4]) = bi;
            *(bf16x4*)(&Wj[row * LDS_STRIDE + c4]) = bj;
        }
    }
    __syncthreads();

    const int wave = tid >> 6;
    const int lane = tid & 63;
    const int wr = (wave >> 1) * 64;   // wave row offset in tile
    const int wc = (wave & 1) * 64;    // wave col offset in tile
    const int l15 = lane & 15;
    const int quad = lane >> 4;

    f32x4 acc[4][4] = {};

    // ---- Gram tile: C[m][n] = sum_k Wi[m][k]*Wj[n][k] via mfma 16x16x32 ----
    for (int kk = 0; kk < D; kk += 32) {
        bf16x8 a[4], b[4];
        for (int ti = 0; ti < 4; ++ti)
            a[ti] = *(const bf16x8*)(&Wi[(wr + ti * 16 + l15) * LDS_STRIDE + kk + quad * 8]);
        for (int tj = 0; tj < 4; ++tj)
            b[tj] = *(const bf16x8*)(&Wj[(wc + tj * 16 + l15) * LDS_STRIDE + kk + quad * 8]);
        for (int ti = 0; ti < 4; ++ti)
            for (int tj = 0; tj < 4; ++tj)
                acc[ti][tj] = __builtin_amdgcn_mfma_f32_16x16x32_bf16(a[ti], b[tj], acc[ti][tj], 0, 0, 0);
    }

    // ---- epilogue: dist = sqrt(max(sq_i + sq_j - 2g, 0)); sum A*dist ----
    // C/D mapping (m89-verified): col = lane&15, row = quad*4 + reg
    float sqi[4][4];
    for (int ti = 0; ti < 4; ++ti)
        for (int r = 0; r < 4; ++r)
            sqi[ti][r] = sq[i0 + wr + ti * 16 + quad * 4 + r];

    float local = 0.0f;
    for (int ti = 0; ti < 4; ++ti) {
        for (int tj = 0; tj < 4; ++tj) {
            const int colg = j0 + wc + tj * 16 + l15;
            const float sqj = sq[colg];
            const float* Arow = A + (size_t)(i0 + wr + ti * 16 + quad * 4) * N + colg;
            for (int r = 0; r < 4; ++r) {
                const float g = acc[ti][tj][r];
                const float d2 = sqi[ti][r] + sqj - 2.0f * g;
                const float dist = sqrtf(fmaxf(d2, 0.0f));
                local += Arow[(size_t)r * N] * dist;
            }
        }
    }

    // ---- block reduce + one atomic ----
    for (int off = 32; off > 0; off >>= 1) local += __shfl_down(local, off, 64);
    __shared__ float red[4];
    if (lane == 0) red[wave] = local;
    __syncthreads();
    if (tid == 0) atomicAdd(out, red[0] + red[1] + red[2] + red[3]);
}

extern "C" void kernel_launch(void* const* d_in, const int* in_sizes, int n_in,
                              void* d_out, int out_size, void* d_ws, size_t ws_size,
                              hipStream_t stream) {
    const float* A = (const float*)d_in[0];
    const float* W = (const float*)d_in[1];
    float* out = (float*)d_out;
    float* sq = (float*)d_ws;  // 8192 floats = 32 KB scratch

    prep_kernel<<<N, D, 0, stream>>>(W, out, sq);
    dim3 grid(N / BN, N / BM);
    lap_kernel<<<grid, 256, 0, stream>>>(A, W, sq, out);
}